// Round 11
// baseline (2959.365 us; speedup 1.0000x reference)
//
#include <hip/hip_runtime.h>
#include <hip/hip_bf16.h>

// 4-layer GCN, N=100000, E=6400000, dims 34->16->16->16->4.
//
// out[i] = b + dinv[i] * sum_{e: dst=i} dinv[src]*h[src]  (incl. self-loop)
// => hp = dinv*(x@W); agg[i] = hp[i] + sum_{in-edges} hp[src]; out = dinv*agg + b.
//
// Round-11: remove the node-level sort (bucket_build2 was latency-bound at
// 7.5% occupancy). Counting sort now keys on (dst-bucket, src-shard) only
// (784 keys); gathers consume gpack segments directly, accumulating into a
// 512x16 LDS tile via ds_add_f32. Degree comes from a cheap per-(bucket,
// shard) histogram pass. Self-loop = LDS tile init from hp (owning shard).

static constexpr int THREADS = 256;
static constexpr int BSHIFT  = 9;     // nodes per dst-bucket = 512
static constexpr int NPB     = 512;
static constexpr int MAXK    = 1024;  // LDS bound on key count (= nbkt*4)
static constexpr int NCHUNK  = 256;   // blocks in edge-streaming passes
static constexpr int EPT     = 8;     // edges per thread in streaming passes
static constexpr int SSHIFT  = 15;    // nodes per src-shard = 32768 (2 MB hp)
static constexpr int NSHARD  = 4;

// ============================ CSR-lite build (counting sort) ================
// key = (dst >> BSHIFT)*NSHARD + (src >> SSHIFT);  gpack = (src<<9)|(dst&511)

__global__ __launch_bounds__(THREADS)
void k_hist(const int* __restrict__ src, const int* __restrict__ dst,
            int* __restrict__ hist_part, int e, int nkey, int chunk) {
    __shared__ int h[MAXK];
    for (int t = threadIdx.x; t < nkey; t += THREADS) h[t] = 0;
    __syncthreads();
    int beg = blockIdx.x * chunk;
    int end = min(e, beg + chunk);
    for (int base = beg; base < end; base += THREADS * EPT) {
        int i = base + (int)threadIdx.x * EPT;
        if (i + EPT <= end) {
            int4 s0 = *(const int4*)(src + i);
            int4 s1 = *(const int4*)(src + i + 4);
            int4 d0 = *(const int4*)(dst + i);
            int4 d1 = *(const int4*)(dst + i + 4);
            atomicAdd(&h[(d0.x >> BSHIFT) * NSHARD + (s0.x >> SSHIFT)], 1);
            atomicAdd(&h[(d0.y >> BSHIFT) * NSHARD + (s0.y >> SSHIFT)], 1);
            atomicAdd(&h[(d0.z >> BSHIFT) * NSHARD + (s0.z >> SSHIFT)], 1);
            atomicAdd(&h[(d0.w >> BSHIFT) * NSHARD + (s0.w >> SSHIFT)], 1);
            atomicAdd(&h[(d1.x >> BSHIFT) * NSHARD + (s1.x >> SSHIFT)], 1);
            atomicAdd(&h[(d1.y >> BSHIFT) * NSHARD + (s1.y >> SSHIFT)], 1);
            atomicAdd(&h[(d1.z >> BSHIFT) * NSHARD + (s1.z >> SSHIFT)], 1);
            atomicAdd(&h[(d1.w >> BSHIFT) * NSHARD + (s1.w >> SSHIFT)], 1);
        } else {
            for (int k = i; k < end; k++)
                atomicAdd(&h[(dst[k] >> BSHIFT) * NSHARD + (src[k] >> SSHIFT)], 1);
        }
    }
    __syncthreads();
    for (int t = threadIdx.x; t < nkey; t += THREADS)
        hist_part[(size_t)blockIdx.x * nkey + t] = h[t];
}

__global__ __launch_bounds__(NCHUNK)
void k_colscan(int* __restrict__ hist_part, int* __restrict__ ktot, int nkey) {
    __shared__ int s[NCHUNK];
    int b = blockIdx.x;
    int v = hist_part[(size_t)threadIdx.x * nkey + b];
    s[threadIdx.x] = v;
    __syncthreads();
    for (int ofs = 1; ofs < NCHUNK; ofs <<= 1) {
        int t = (threadIdx.x >= ofs) ? s[threadIdx.x - ofs] : 0;
        __syncthreads();
        s[threadIdx.x] += t;
        __syncthreads();
    }
    hist_part[(size_t)threadIdx.x * nkey + b] = s[threadIdx.x] - v;  // exclusive
    if (threadIdx.x == NCHUNK - 1) ktot[b] = s[NCHUNK - 1];
}

__global__ __launch_bounds__(1024)
void k_scan_b(const int* __restrict__ ktot, int* __restrict__ kbase,
              int nkey, int e) {
    __shared__ int s[1024];
    int v = (threadIdx.x < nkey) ? ktot[threadIdx.x] : 0;
    s[threadIdx.x] = v;
    __syncthreads();
    for (int ofs = 1; ofs < 1024; ofs <<= 1) {
        int t = (threadIdx.x >= ofs) ? s[threadIdx.x - ofs] : 0;
        __syncthreads();
        s[threadIdx.x] += t;
        __syncthreads();
    }
    if (threadIdx.x < nkey) kbase[threadIdx.x] = s[threadIdx.x] - v;
    if (threadIdx.x == 0) kbase[nkey] = e;
}

__global__ __launch_bounds__(THREADS)
void k_scatter_bkt(const int* __restrict__ src, const int* __restrict__ dst,
                   const int* __restrict__ offs_part, const int* __restrict__ kbase,
                   int* __restrict__ gpack, int e, int nkey, int chunk) {
    __shared__ int curs[MAXK];
    for (int t = threadIdx.x; t < nkey; t += THREADS)
        curs[t] = kbase[t] + offs_part[(size_t)blockIdx.x * nkey + t];
    __syncthreads();
    int beg = blockIdx.x * chunk;
    int end = min(e, beg + chunk);
    for (int base = beg; base < end; base += THREADS * EPT) {
        int i = base + (int)threadIdx.x * EPT;
        if (i + EPT <= end) {
            int4 s0 = *(const int4*)(src + i);
            int4 s1 = *(const int4*)(src + i + 4);
            int4 d0 = *(const int4*)(dst + i);
            int4 d1 = *(const int4*)(dst + i + 4);
            int p0 = atomicAdd(&curs[(d0.x >> BSHIFT) * NSHARD + (s0.x >> SSHIFT)], 1);
            int p1 = atomicAdd(&curs[(d0.y >> BSHIFT) * NSHARD + (s0.y >> SSHIFT)], 1);
            int p2 = atomicAdd(&curs[(d0.z >> BSHIFT) * NSHARD + (s0.z >> SSHIFT)], 1);
            int p3 = atomicAdd(&curs[(d0.w >> BSHIFT) * NSHARD + (s0.w >> SSHIFT)], 1);
            int p4 = atomicAdd(&curs[(d1.x >> BSHIFT) * NSHARD + (s1.x >> SSHIFT)], 1);
            int p5 = atomicAdd(&curs[(d1.y >> BSHIFT) * NSHARD + (s1.y >> SSHIFT)], 1);
            int p6 = atomicAdd(&curs[(d1.z >> BSHIFT) * NSHARD + (s1.z >> SSHIFT)], 1);
            int p7 = atomicAdd(&curs[(d1.w >> BSHIFT) * NSHARD + (s1.w >> SSHIFT)], 1);
            gpack[p0] = (s0.x << BSHIFT) | (d0.x & (NPB - 1));
            gpack[p1] = (s0.y << BSHIFT) | (d0.y & (NPB - 1));
            gpack[p2] = (s0.z << BSHIFT) | (d0.z & (NPB - 1));
            gpack[p3] = (s0.w << BSHIFT) | (d0.w & (NPB - 1));
            gpack[p4] = (s1.x << BSHIFT) | (d1.x & (NPB - 1));
            gpack[p5] = (s1.y << BSHIFT) | (d1.y & (NPB - 1));
            gpack[p6] = (s1.z << BSHIFT) | (d1.z & (NPB - 1));
            gpack[p7] = (s1.w << BSHIFT) | (d1.w & (NPB - 1));
        } else {
            for (int k = i; k < end; k++) {
                int d = dst[k], s = src[k];
                int p = atomicAdd(&curs[(d >> BSHIFT) * NSHARD + (s >> SSHIFT)], 1);
                gpack[p] = (s << BSHIFT) | (d & (NPB - 1));
            }
        }
    }
}

// ---- per-(bucket,shard) degree histogram -> deg_part[shard][node] ----
__global__ __launch_bounds__(THREADS)
void k_bucket_deg(const int* __restrict__ gpack, const int* __restrict__ kbase,
                  int* __restrict__ deg_part, int n) {
    __shared__ int hist[NPB];
    int shard  = blockIdx.x & (NSHARD - 1);
    int bucket = blockIdx.x >> 2;
    int node0  = bucket << BSHIFT;
    int tid = threadIdx.x;
    for (int t = tid; t < NPB; t += THREADS) hist[t] = 0;
    __syncthreads();
    int ebeg = kbase[blockIdx.x];
    int eend = kbase[blockIdx.x + 1];
    int i = ebeg + tid;
    for (; i + 3 * THREADS < eend; i += 4 * THREADS) {
        int g0 = gpack[i];
        int g1 = gpack[i + THREADS];
        int g2 = gpack[i + 2 * THREADS];
        int g3 = gpack[i + 3 * THREADS];
        atomicAdd(&hist[g0 & (NPB - 1)], 1);
        atomicAdd(&hist[g1 & (NPB - 1)], 1);
        atomicAdd(&hist[g2 & (NPB - 1)], 1);
        atomicAdd(&hist[g3 & (NPB - 1)], 1);
    }
    for (; i < eend; i += THREADS) atomicAdd(&hist[gpack[i] & (NPB - 1)], 1);
    __syncthreads();
    for (int t = tid; t < NPB; t += THREADS) {
        int node = node0 + t;
        if (node < n) deg_part[(size_t)shard * n + node] = hist[t];
    }
}

__global__ __launch_bounds__(THREADS)
void k_dinv4(const int* __restrict__ deg_part, float* __restrict__ dinv, int n) {
    int i = blockIdx.x * THREADS + threadIdx.x;
    if (i >= n) return;
    int d = deg_part[i] + deg_part[(size_t)n + i] +
            deg_part[2 * (size_t)n + i] + deg_part[3 * (size_t)n + i] + 1;
    dinv[i] = 1.0f / sqrtf((float)d);
}

// ====================== layer kernels =======================================

__global__ __launch_bounds__(THREADS)
void k_layer_in(const float* __restrict__ x, const float* __restrict__ W,
                const float* __restrict__ dinv, float* __restrict__ hp, int n) {
    __shared__ float sW[34 * 16];
    for (int t = threadIdx.x; t < 34 * 16; t += THREADS) sW[t] = W[t];
    __syncthreads();
    int i = blockIdx.x * THREADS + threadIdx.x;
    if (i >= n) return;
    float di = dinv[i];
    float acc[16];
    #pragma unroll
    for (int j = 0; j < 16; j++) acc[j] = 0.0f;
    const float* xi = x + (size_t)i * 34;
    #pragma unroll
    for (int k = 0; k < 34; k++) {
        float xk = xi[k];
        #pragma unroll
        for (int j = 0; j < 16; j++) acc[j] = fmaf(xk, sW[k * 16 + j], acc[j]);
    }
    float4* o = (float4*)(hp + (size_t)i * 16);
    o[0] = make_float4(acc[0] * di, acc[1] * di, acc[2] * di, acc[3] * di);
    o[1] = make_float4(acc[4] * di, acc[5] * di, acc[6] * di, acc[7] * di);
    o[2] = make_float4(acc[8] * di, acc[9] * di, acc[10] * di, acc[11] * di);
    o[3] = make_float4(acc[12] * di, acc[13] * di, acc[14] * di, acc[15] * di);
}

__global__ __launch_bounds__(THREADS)
void k_layer_mid2(const float* __restrict__ part, const float* __restrict__ W,
                  const float* __restrict__ bprev, const float* __restrict__ dinv,
                  float* __restrict__ hp, int n) {
    __shared__ float sW[16 * 16];
    __shared__ float sB[16];
    for (int t = threadIdx.x; t < 16 * 16; t += THREADS) sW[t] = W[t];
    if (threadIdx.x < 16) sB[threadIdx.x] = bprev[threadIdx.x];
    __syncthreads();
    int i = blockIdx.x * THREADS + threadIdx.x;
    if (i >= n) return;
    float di = dinv[i];
    size_t stride = (size_t)n * 4;   // float4 stride between shard planes
    const float4* p = (const float4*)(part) + (size_t)i * 4;
    float4 a0 = p[0], a1 = p[1], a2 = p[2], a3 = p[3];
    #pragma unroll
    for (int s = 1; s < NSHARD; s++) {
        float4 q0 = p[s * stride + 0], q1 = p[s * stride + 1];
        float4 q2 = p[s * stride + 2], q3 = p[s * stride + 3];
        a0.x += q0.x; a0.y += q0.y; a0.z += q0.z; a0.w += q0.w;
        a1.x += q1.x; a1.y += q1.y; a1.z += q1.z; a1.w += q1.w;
        a2.x += q2.x; a2.y += q2.y; a2.z += q2.z; a2.w += q2.w;
        a3.x += q3.x; a3.y += q3.y; a3.z += q3.z; a3.w += q3.w;
    }
    float xin[16] = {a0.x, a0.y, a0.z, a0.w, a1.x, a1.y, a1.z, a1.w,
                     a2.x, a2.y, a2.z, a2.w, a3.x, a3.y, a3.z, a3.w};
    #pragma unroll
    for (int k = 0; k < 16; k++)
        xin[k] = fmaxf(fmaf(di, xin[k], sB[k]), 0.0f);
    float acc[16];
    #pragma unroll
    for (int j = 0; j < 16; j++) acc[j] = 0.0f;
    #pragma unroll
    for (int k = 0; k < 16; k++) {
        float xk = xin[k];
        #pragma unroll
        for (int j = 0; j < 16; j++) acc[j] = fmaf(xk, sW[k * 16 + j], acc[j]);
    }
    float4* o = (float4*)(hp + (size_t)i * 16);
    o[0] = make_float4(acc[0] * di, acc[1] * di, acc[2] * di, acc[3] * di);
    o[1] = make_float4(acc[4] * di, acc[5] * di, acc[6] * di, acc[7] * di);
    o[2] = make_float4(acc[8] * di, acc[9] * di, acc[10] * di, acc[11] * di);
    o[3] = make_float4(acc[12] * di, acc[13] * di, acc[14] * di, acc[15] * di);
}

__global__ __launch_bounds__(THREADS)
void k_layer_last2(const float* __restrict__ part, const float* __restrict__ W,
                   const float* __restrict__ bprev, const float* __restrict__ dinv,
                   float* __restrict__ hp4, int n) {
    __shared__ float sW[16 * 4];
    __shared__ float sB[16];
    for (int t = threadIdx.x; t < 16 * 4; t += THREADS) sW[t] = W[t];
    if (threadIdx.x < 16) sB[threadIdx.x] = bprev[threadIdx.x];
    __syncthreads();
    int i = blockIdx.x * THREADS + threadIdx.x;
    if (i >= n) return;
    float di = dinv[i];
    size_t stride = (size_t)n * 4;
    const float4* p = (const float4*)(part) + (size_t)i * 4;
    float4 a0 = p[0], a1 = p[1], a2 = p[2], a3 = p[3];
    #pragma unroll
    for (int s = 1; s < NSHARD; s++) {
        float4 q0 = p[s * stride + 0], q1 = p[s * stride + 1];
        float4 q2 = p[s * stride + 2], q3 = p[s * stride + 3];
        a0.x += q0.x; a0.y += q0.y; a0.z += q0.z; a0.w += q0.w;
        a1.x += q1.x; a1.y += q1.y; a1.z += q1.z; a1.w += q1.w;
        a2.x += q2.x; a2.y += q2.y; a2.z += q2.z; a2.w += q2.w;
        a3.x += q3.x; a3.y += q3.y; a3.z += q3.z; a3.w += q3.w;
    }
    float xin[16] = {a0.x, a0.y, a0.z, a0.w, a1.x, a1.y, a1.z, a1.w,
                     a2.x, a2.y, a2.z, a2.w, a3.x, a3.y, a3.z, a3.w};
    #pragma unroll
    for (int k = 0; k < 16; k++)
        xin[k] = fmaxf(fmaf(di, xin[k], sB[k]), 0.0f);
    float acc[4];
    #pragma unroll
    for (int j = 0; j < 4; j++) acc[j] = 0.0f;
    #pragma unroll
    for (int k = 0; k < 16; k++) {
        float xk = xin[k];
        #pragma unroll
        for (int j = 0; j < 4; j++) acc[j] = fmaf(xk, sW[k * 4 + j], acc[j]);
    }
    *(float4*)(hp4 + (size_t)i * 4) =
        make_float4(acc[0] * di, acc[1] * di, acc[2] * di, acc[3] * di);
}

// ====================== bucket gather (LDS tile + ds_add) ===================
// one block per (bucket, shard); shard = blockIdx&3 -> XCD pinning of the
// 2 MB hp slice. agg[512][16] in LDS; fp32 LDS atomics; edges read once,
// coalesced. Self-loop: tile initialized from hp for the owning shard.

__global__ __launch_bounds__(THREADS)
void k_gather16b(const int* __restrict__ gpack, const int* __restrict__ kbase,
                 const float* __restrict__ hp, float* __restrict__ part, int n) {
    __shared__ float agg[NPB * 16];   // 32 KB
    int shard  = blockIdx.x & (NSHARD - 1);
    int bucket = blockIdx.x >> 2;
    int node0  = bucket << BSHIFT;
    int tid = threadIdx.x;
    bool own = ((node0 >> SSHIFT) == shard);   // bucket wholly in one shard

    {   // init tile (self-loop for owning shard)
        int r0 = tid >> 4, c = tid & 15;
        for (int r = r0; r < NPB; r += 16) {
            int node = node0 + r;
            float v = 0.0f;
            if (own && node < n) v = hp[(size_t)node * 16 + c];
            agg[r * 16 + c] = v;
        }
    }
    __syncthreads();

    int ebeg = kbase[blockIdx.x];
    int eend = kbase[blockIdx.x + 1];
    int wid = tid >> 6;
    int q   = (tid >> 4) & 3;    // quarter within wave
    int c   = tid & 15;          // channel

    // wave covers 32 edges/iter (8 per quarter), 4 waves -> 128/block-iter
    for (int base = ebeg + wid * 32; base < eend; base += 128) {
        int ilim = eend - 1;
        int i0 = base + q * 8;
        int g0 = gpack[min(i0 + 0, ilim)];
        int g1 = gpack[min(i0 + 1, ilim)];
        int g2 = gpack[min(i0 + 2, ilim)];
        int g3 = gpack[min(i0 + 3, ilim)];
        int g4 = gpack[min(i0 + 4, ilim)];
        int g5 = gpack[min(i0 + 5, ilim)];
        int g6 = gpack[min(i0 + 6, ilim)];
        int g7 = gpack[min(i0 + 7, ilim)];
        float v0 = hp[(size_t)(g0 >> BSHIFT) * 16 + c];
        float v1 = hp[(size_t)(g1 >> BSHIFT) * 16 + c];
        float v2 = hp[(size_t)(g2 >> BSHIFT) * 16 + c];
        float v3 = hp[(size_t)(g3 >> BSHIFT) * 16 + c];
        float v4 = hp[(size_t)(g4 >> BSHIFT) * 16 + c];
        float v5 = hp[(size_t)(g5 >> BSHIFT) * 16 + c];
        float v6 = hp[(size_t)(g6 >> BSHIFT) * 16 + c];
        float v7 = hp[(size_t)(g7 >> BSHIFT) * 16 + c];
        if (i0 + 0 < eend) atomicAdd(&agg[(g0 & (NPB - 1)) * 16 + c], v0);
        if (i0 + 1 < eend) atomicAdd(&agg[(g1 & (NPB - 1)) * 16 + c], v1);
        if (i0 + 2 < eend) atomicAdd(&agg[(g2 & (NPB - 1)) * 16 + c], v2);
        if (i0 + 3 < eend) atomicAdd(&agg[(g3 & (NPB - 1)) * 16 + c], v3);
        if (i0 + 4 < eend) atomicAdd(&agg[(g4 & (NPB - 1)) * 16 + c], v4);
        if (i0 + 5 < eend) atomicAdd(&agg[(g5 & (NPB - 1)) * 16 + c], v5);
        if (i0 + 6 < eend) atomicAdd(&agg[(g6 & (NPB - 1)) * 16 + c], v6);
        if (i0 + 7 < eend) atomicAdd(&agg[(g7 & (NPB - 1)) * 16 + c], v7);
    }
    __syncthreads();

    {   // write tile to partial plane
        int r0 = tid >> 4, c2 = tid & 15;
        for (int r = r0; r < NPB; r += 16) {
            int node = node0 + r;
            if (node < n)
                part[((size_t)shard * n + node) * 16 + c2] = agg[r * 16 + c2];
        }
    }
}

// final layer: same pattern, 4 channels -> part4[shard][node][4]
__global__ __launch_bounds__(THREADS)
void k_gather4b(const int* __restrict__ gpack, const int* __restrict__ kbase,
                const float* __restrict__ hp4, float* __restrict__ part4, int n) {
    __shared__ float agg[NPB * 4];   // 8 KB
    int shard  = blockIdx.x & (NSHARD - 1);
    int bucket = blockIdx.x >> 2;
    int node0  = bucket << BSHIFT;
    int tid = threadIdx.x;
    bool own = ((node0 >> SSHIFT) == shard);

    {   // init (self-loop for owning shard)
        int r0 = tid >> 2, c = tid & 3;
        for (int r = r0; r < NPB; r += 64) {
            int node = node0 + r;
            float v = 0.0f;
            if (own && node < n) v = hp4[(size_t)node * 4 + c];
            agg[r * 4 + c] = v;
        }
    }
    __syncthreads();

    int ebeg = kbase[blockIdx.x];
    int eend = kbase[blockIdx.x + 1];
    int wid = tid >> 6;
    int lane = tid & 63;
    int es = lane >> 2;   // 16 edge slots
    int c  = lane & 3;    // channel

    // wave covers 64 edges/iter (4 slots-rounds x 16), 4 waves -> 256/iter
    for (int base = ebeg + wid * 64; base < eend; base += 256) {
        int ilim = eend - 1;
        int i0 = base + es;
        int i1 = base + 16 + es;
        int i2 = base + 32 + es;
        int i3 = base + 48 + es;
        int g0 = gpack[min(i0, ilim)];
        int g1 = gpack[min(i1, ilim)];
        int g2 = gpack[min(i2, ilim)];
        int g3 = gpack[min(i3, ilim)];
        float v0 = hp4[(size_t)(g0 >> BSHIFT) * 4 + c];
        float v1 = hp4[(size_t)(g1 >> BSHIFT) * 4 + c];
        float v2 = hp4[(size_t)(g2 >> BSHIFT) * 4 + c];
        float v3 = hp4[(size_t)(g3 >> BSHIFT) * 4 + c];
        if (i0 < eend) atomicAdd(&agg[(g0 & (NPB - 1)) * 4 + c], v0);
        if (i1 < eend) atomicAdd(&agg[(g1 & (NPB - 1)) * 4 + c], v1);
        if (i2 < eend) atomicAdd(&agg[(g2 & (NPB - 1)) * 4 + c], v2);
        if (i3 < eend) atomicAdd(&agg[(g3 & (NPB - 1)) * 4 + c], v3);
    }
    __syncthreads();

    {
        int r0 = tid >> 2, c2 = tid & 3;
        for (int r = r0; r < NPB; r += 64) {
            int node = node0 + r;
            if (node < n)
                part4[((size_t)shard * n + node) * 4 + c2] = agg[r * 4 + c2];
        }
    }
}

// out = dinv * (sum of 4 partial planes) + b4
__global__ __launch_bounds__(THREADS)
void k_final4(const float* __restrict__ part4, const float* __restrict__ dinv,
              const float* __restrict__ b4, float* __restrict__ outp, int n) {
    int i = blockIdx.x * THREADS + threadIdx.x;
    if (i >= n) return;
    size_t stride = (size_t)n;   // float4 stride between planes
    const float4* p = (const float4*)(part4) + i;
    float4 a = p[0];
    #pragma unroll
    for (int s = 1; s < NSHARD; s++) {
        float4 q = p[s * stride];
        a.x += q.x; a.y += q.y; a.z += q.z; a.w += q.w;
    }
    float di = dinv[i];
    *(float4*)(outp + (size_t)i * 4) =
        make_float4(fmaf(di, a.x, b4[0]), fmaf(di, a.y, b4[1]),
                    fmaf(di, a.z, b4[2]), fmaf(di, a.w, b4[3]));
}

// ========================= fallback path kernels ============================

__global__ __launch_bounds__(THREADS)
void k_zero(int* __restrict__ p, int n) {
    int i = blockIdx.x * THREADS + threadIdx.x;
    if (i < n) p[i] = 0;
}

__global__ __launch_bounds__(THREADS)
void k_count_deg(const int* __restrict__ dst, int* __restrict__ deg, int e) {
    int i = blockIdx.x * THREADS + threadIdx.x;
    if (i >= e) return;
    atomicAdd(&deg[dst[i]], 1);
}

__global__ __launch_bounds__(THREADS)
void k_dinv(const int* __restrict__ deg, float* __restrict__ dinv, int n) {
    int i = blockIdx.x * THREADS + threadIdx.x;
    if (i < n) dinv[i] = 1.0f / sqrtf((float)(deg[i] + 1));
}

__global__ __launch_bounds__(THREADS)
void k_scan1(const int* __restrict__ deg, int* __restrict__ rowptr,
             int* __restrict__ bsum, int n) {
    __shared__ int s[THREADS];
    int i = blockIdx.x * THREADS + threadIdx.x;
    int v = (i < n) ? deg[i] : 0;
    s[threadIdx.x] = v;
    __syncthreads();
    for (int ofs = 1; ofs < THREADS; ofs <<= 1) {
        int t = (threadIdx.x >= ofs) ? s[threadIdx.x - ofs] : 0;
        __syncthreads();
        s[threadIdx.x] += t;
        __syncthreads();
    }
    if (i < n) rowptr[i] = s[threadIdx.x] - v;
    if (threadIdx.x == THREADS - 1) bsum[blockIdx.x] = s[THREADS - 1];
}

__global__ __launch_bounds__(1024)
void k_scan2(int* __restrict__ bsum, int nb) {
    __shared__ int s[1024];
    int v = (threadIdx.x < nb) ? bsum[threadIdx.x] : 0;
    s[threadIdx.x] = v;
    __syncthreads();
    for (int ofs = 1; ofs < 1024; ofs <<= 1) {
        int t = (threadIdx.x >= ofs) ? s[threadIdx.x - ofs] : 0;
        __syncthreads();
        s[threadIdx.x] += t;
        __syncthreads();
    }
    if (threadIdx.x < nb) bsum[threadIdx.x] = s[threadIdx.x] - v;
}

__global__ __launch_bounds__(THREADS)
void k_scan3(int* __restrict__ rowptr, const int* __restrict__ bsum,
             int* __restrict__ cursor, int n, int e) {
    int i = blockIdx.x * THREADS + threadIdx.x;
    if (i < n) {
        int r = rowptr[i] + bsum[blockIdx.x];
        rowptr[i] = r;
        cursor[i] = r;
    }
    if (i == 0) rowptr[n] = e;
}

__global__ __launch_bounds__(THREADS)
void k_fill_cursor(const int* __restrict__ src, const int* __restrict__ dst,
                   int* __restrict__ cursor, int* __restrict__ csr, int e) {
    int i = blockIdx.x * THREADS + threadIdx.x;
    if (i >= e) return;
    int pos = atomicAdd(&cursor[dst[i]], 1);
    csr[pos] = src[i];
}

template<int DIN, int DOUT, bool TRANSFORM>
__global__ __launch_bounds__(THREADS)
void k_layer(const float* __restrict__ in, const float* __restrict__ W,
             const float* __restrict__ bprev, const float* __restrict__ dinv,
             float* __restrict__ hp, int n) {
    __shared__ float sW[DIN * DOUT];
    for (int t = threadIdx.x; t < DIN * DOUT; t += THREADS) sW[t] = W[t];
    __syncthreads();
    int i = blockIdx.x * THREADS + threadIdx.x;
    if (i >= n) return;
    float di = dinv[i];
    float xin[DIN];
    #pragma unroll
    for (int k = 0; k < DIN; k++) xin[k] = in[(size_t)i * DIN + k];
    if constexpr (TRANSFORM) {
        #pragma unroll
        for (int k = 0; k < DIN; k++)
            xin[k] = fmaxf(fmaf(di, xin[k], bprev[k]), 0.0f);
    }
    float acc[DOUT];
    #pragma unroll
    for (int j = 0; j < DOUT; j++) acc[j] = 0.0f;
    #pragma unroll
    for (int k = 0; k < DIN; k++) {
        float xk = xin[k];
        #pragma unroll
        for (int j = 0; j < DOUT; j++) acc[j] = fmaf(xk, sW[k * DOUT + j], acc[j]);
    }
    #pragma unroll
    for (int j = 0; j < DOUT; j++) hp[(size_t)i * DOUT + j] = acc[j] * di;
}

template<int D, bool FINAL>
__global__ __launch_bounds__(THREADS)
void k_gather(const int* __restrict__ rowptr, const int* __restrict__ csr,
              const float* __restrict__ hp, float* __restrict__ outp,
              const float* __restrict__ dinv, const float* __restrict__ bias,
              int n) {
    int tid  = blockIdx.x * THREADS + threadIdx.x;
    int row  = tid / D;
    int lane = tid & (D - 1);
    if (row >= n) return;
    int base = (threadIdx.x & 63) & ~(D - 1);
    int beg = rowptr[row];
    int end = rowptr[row + 1];
    float a0 = hp[(size_t)row * D + lane];
    float a1 = 0.f, a2 = 0.f, a3 = 0.f;
    int e = beg;
    for (; e + D <= end; e += D) {
        int s = csr[e + lane];
        #pragma unroll
        for (int k = 0; k < D; k += 4) {
            int s0 = __shfl(s, base + k + 0, 64);
            int s1 = __shfl(s, base + k + 1, 64);
            int s2 = __shfl(s, base + k + 2, 64);
            int s3 = __shfl(s, base + k + 3, 64);
            a0 += hp[(size_t)s0 * D + lane];
            a1 += hp[(size_t)s1 * D + lane];
            a2 += hp[(size_t)s2 * D + lane];
            a3 += hp[(size_t)s3 * D + lane];
        }
    }
    if (e < end) {
        int idx = e + lane;
        int s = (idx < end) ? csr[idx] : 0;
        int cnt = end - e;
        for (int k = 0; k < cnt; k++) {
            int sk = __shfl(s, base + k, 64);
            a0 += hp[(size_t)sk * D + lane];
        }
    }
    float acc = (a0 + a1) + (a2 + a3);
    if constexpr (FINAL) {
        outp[(size_t)row * D + lane] = fmaf(dinv[row], acc, bias[lane]);
    } else {
        outp[(size_t)row * D + lane] = acc;
    }
}

// ---------------------------------------------------------------------------

extern "C" void kernel_launch(void* const* d_in, const int* in_sizes, int n_in,
                              void* d_out, int out_size, void* d_ws, size_t ws_size,
                              hipStream_t stream) {
    const float* x   = (const float*)d_in[0];
    const int*   ei  = (const int*)d_in[1];   // int32 per harness conversion
    const float* W1  = (const float*)d_in[2];
    const float* b1  = (const float*)d_in[3];
    const float* W2  = (const float*)d_in[4];
    const float* b2  = (const float*)d_in[5];
    const float* W3  = (const float*)d_in[6];
    const float* b3  = (const float*)d_in[7];
    const float* W4  = (const float*)d_in[8];
    const float* b4  = (const float*)d_in[9];
    float*       out = (float*)d_out;

    const int N = in_sizes[0] / 34;
    const int E = in_sizes[1] / 2;
    const int* src = ei;
    const int* dst = ei + E;

    const int gN = (N + THREADS - 1) / THREADS;

    const int nbkt  = (N + NPB - 1) >> BSHIFT;
    const int nkey  = nbkt * NSHARD;
    const int chunk = (((E + NCHUNK - 1) / NCHUNK) + EPT - 1) & ~(EPT - 1);

    // ---- fast-path carve ----
    {
        char* ws = (char*)d_ws;
        size_t off = 0;
        auto alloc = [&](size_t bytes) -> void* {
            void* p = ws + off;
            off += (bytes + 255) & ~(size_t)255;
            return p;
        };
        float* dinv     = (float*)alloc((size_t)N * 4);
        float* hp       = (float*)alloc((size_t)N * 16 * 4);
        float* part     = (float*)alloc((size_t)NSHARD * N * 16 * 4);
        float* hp4      = (float*)alloc((size_t)N * 4 * 4);
        float* part4    = (float*)alloc((size_t)NSHARD * N * 4 * 4);
        int*   gpack    = (int*)  alloc((size_t)E * 4);
        int*   deg_part = (int*)  alloc((size_t)NSHARD * N * 4);
        int*   offsp    = (int*)  alloc((size_t)NCHUNK * nkey * 4);
        int*   ktot     = (int*)  alloc((size_t)nkey * 4);
        int*   kbase    = (int*)  alloc((size_t)(nkey + 1) * 4);

        bool aligned16 = (((uintptr_t)src & 15) == 0) && (((uintptr_t)dst & 15) == 0);
        bool fast_ok = (nkey <= MAXK) && (off <= ws_size) && aligned16 &&
                       (N <= (1 << (31 - BSHIFT - 1))) &&   // src<<9 no overflow
                       (N <= (NSHARD << SSHIFT));           // shard id < NSHARD

        if (fast_ok) {
            // ---- counting sort by (dst-bucket, src-shard) ----
            k_hist       <<<NCHUNK, THREADS, 0, stream>>>(src, dst, offsp, E, nkey, chunk);
            k_colscan    <<<nkey, NCHUNK, 0, stream>>>(offsp, ktot, nkey);
            k_scan_b     <<<1, 1024, 0, stream>>>(ktot, kbase, nkey, E);
            k_scatter_bkt<<<NCHUNK, THREADS, 0, stream>>>(src, dst, offsp, kbase,
                                                          gpack, E, nkey, chunk);
            // ---- degree + dinv ----
            k_bucket_deg<<<nkey, THREADS, 0, stream>>>(gpack, kbase, deg_part, N);
            k_dinv4     <<<gN, THREADS, 0, stream>>>(deg_part, dinv, N);

            // ---- layers ----
            k_layer_in  <<<gN, THREADS, 0, stream>>>(x, W1, dinv, hp, N);
            k_gather16b <<<nkey, THREADS, 0, stream>>>(gpack, kbase, hp, part, N);

            k_layer_mid2<<<gN, THREADS, 0, stream>>>(part, W2, b1, dinv, hp, N);
            k_gather16b <<<nkey, THREADS, 0, stream>>>(gpack, kbase, hp, part, N);

            k_layer_mid2<<<gN, THREADS, 0, stream>>>(part, W3, b2, dinv, hp, N);
            k_gather16b <<<nkey, THREADS, 0, stream>>>(gpack, kbase, hp, part, N);

            k_layer_last2<<<gN, THREADS, 0, stream>>>(part, W4, b3, dinv, hp4, N);
            k_gather4b   <<<nkey, THREADS, 0, stream>>>(gpack, kbase, hp4, part4, N);
            k_final4     <<<gN, THREADS, 0, stream>>>(part4, dinv, b4, out, N);
            return;
        }
    }

    // ---- fallback: cursor-atomic CSR path, unified layout ----
    {
        char* ws = (char*)d_ws;
        size_t off = 0;
        auto alloc = [&](size_t bytes) -> void* {
            void* p = ws + off;
            off += (bytes + 255) & ~(size_t)255;
            return p;
        };
        int*   deg    = (int*)  alloc((size_t)N * 4);
        float* dinv   = (float*)alloc((size_t)N * 4);
        float* bufA   = (float*)alloc((size_t)N * 16 * 4);
        float* bufB   = (float*)alloc((size_t)N * 16 * 4);
        int*   rowptr = (int*)  alloc((size_t)(N + 1) * 4);
        int*   cursor = (int*)  alloc((size_t)N * 4);
        const int nb  = (N + THREADS - 1) / THREADS;
        int*   bsum   = (int*)  alloc((size_t)nb * 4);
        int*   csr    = (int*)  alloc((size_t)E * 4);

        const int gE  = (E + THREADS - 1) / THREADS;
        const int g16 = (int)(((size_t)N * 16 + THREADS - 1) / THREADS);
        const int g4  = (int)(((size_t)N * 4 + THREADS - 1) / THREADS);

        k_zero<<<gN, THREADS, 0, stream>>>(deg, N);
        k_count_deg<<<gE, THREADS, 0, stream>>>(dst, deg, E);
        k_dinv<<<gN, THREADS, 0, stream>>>(deg, dinv, N);
        k_scan1<<<nb, THREADS, 0, stream>>>(deg, rowptr, bsum, N);
        k_scan2<<<1, 1024, 0, stream>>>(bsum, nb);
        k_scan3<<<nb, THREADS, 0, stream>>>(rowptr, bsum, cursor, N, E);
        k_fill_cursor<<<gE, THREADS, 0, stream>>>(src, dst, cursor, csr, E);

        k_layer<34, 16, false><<<gN, THREADS, 0, stream>>>(x, W1, nullptr, dinv, bufA, N);
        k_gather<16, false><<<g16, THREADS, 0, stream>>>(rowptr, csr, bufA, bufB, nullptr, nullptr, N);

        k_layer<16, 16, true><<<gN, THREADS, 0, stream>>>(bufB, W2, b1, dinv, bufA, N);
        k_gather<16, false><<<g16, THREADS, 0, stream>>>(rowptr, csr, bufA, bufB, nullptr, nullptr, N);

        k_layer<16, 16, true><<<gN, THREADS, 0, stream>>>(bufB, W3, b2, dinv, bufA, N);
        k_gather<16, false><<<g16, THREADS, 0, stream>>>(rowptr, csr, bufA, bufB, nullptr, nullptr, N);

        k_layer<16, 4, true><<<gN, THREADS, 0, stream>>>(bufB, W4, b3, dinv, bufA, N);
        k_gather<4, true><<<g4, THREADS, 0, stream>>>(rowptr, csr, bufA, out, dinv, b4, N);
    }
}

// Round 12
// 314.979 us; speedup vs baseline: 9.3954x; 9.3954x over previous
//
#include <hip/hip_runtime.h>
#include <hip/hip_bf16.h>

// 4-layer GCN, N=100000, E=6400000, dims 34->16->16->16->4.
//
// out[i] = b + dinv[i] * sum_{e: dst=i} dinv[src]*h[src]  (incl. self-loop)
// => hp = dinv*(x@W); agg[i] = hp[i] + sum_{in-edges} hp[src]; out = dinv*agg + b.
//
// Round-12: revert to r9 structure (proven 340us; r11's fp32-LDS-atomic gather
// hit a flat-atomic serialization pathology). Fixes on the sort side only:
//  - buckets of 128 nodes + NCHUNK=128: scatter runs = 64 edges = 2 full lines
//  - bucket_build split: k_rowptr2 (hist+scan only, streaming) and
//    k_fill_staged (whole-bucket LDS staging -> ONE sequential csr store)

static constexpr int THREADS   = 256;
static constexpr int BSHIFT    = 7;     // nodes per dst-bucket = 128
static constexpr int NPB       = 128;
static constexpr int MAXB      = 1024;  // LDS bound (nbkt <= MAXB)
static constexpr int NCHUNK    = 128;   // blocks in edge-streaming passes
static constexpr int EPT       = 8;     // edges per thread in streaming passes
static constexpr int SSHIFT    = 15;    // nodes per src-shard = 32768 (2 MB hp)
static constexpr int NSHARD    = 4;
static constexpr int STAGE_CAP = 10240; // staged edges per bucket (40 KB)

// ============================ CSR build (counting sort) =====================

__global__ __launch_bounds__(THREADS)
void k_hist(const int* __restrict__ dst, int* __restrict__ hist_part,
            int e, int nbkt, int chunk) {
    __shared__ int h[MAXB];
    for (int t = threadIdx.x; t < nbkt; t += THREADS) h[t] = 0;
    __syncthreads();
    int beg = blockIdx.x * chunk;
    int end = min(e, beg + chunk);
    for (int base = beg; base < end; base += THREADS * EPT) {
        int i = base + (int)threadIdx.x * EPT;
        if (i + EPT <= end) {
            int4 d0 = *(const int4*)(dst + i);
            int4 d1 = *(const int4*)(dst + i + 4);
            atomicAdd(&h[d0.x >> BSHIFT], 1);
            atomicAdd(&h[d0.y >> BSHIFT], 1);
            atomicAdd(&h[d0.z >> BSHIFT], 1);
            atomicAdd(&h[d0.w >> BSHIFT], 1);
            atomicAdd(&h[d1.x >> BSHIFT], 1);
            atomicAdd(&h[d1.y >> BSHIFT], 1);
            atomicAdd(&h[d1.z >> BSHIFT], 1);
            atomicAdd(&h[d1.w >> BSHIFT], 1);
        } else {
            for (int k = i; k < end; k++) atomicAdd(&h[dst[k] >> BSHIFT], 1);
        }
    }
    __syncthreads();
    for (int t = threadIdx.x; t < nbkt; t += THREADS)
        hist_part[(size_t)blockIdx.x * nbkt + t] = h[t];
}

__global__ __launch_bounds__(NCHUNK)
void k_colscan(int* __restrict__ hist_part, int* __restrict__ btot, int nbkt) {
    __shared__ int s[NCHUNK];
    int b = blockIdx.x;
    int v = hist_part[(size_t)threadIdx.x * nbkt + b];
    s[threadIdx.x] = v;
    __syncthreads();
    for (int ofs = 1; ofs < NCHUNK; ofs <<= 1) {
        int t = (threadIdx.x >= ofs) ? s[threadIdx.x - ofs] : 0;
        __syncthreads();
        s[threadIdx.x] += t;
        __syncthreads();
    }
    hist_part[(size_t)threadIdx.x * nbkt + b] = s[threadIdx.x] - v;  // exclusive
    if (threadIdx.x == NCHUNK - 1) btot[b] = s[NCHUNK - 1];
}

__global__ __launch_bounds__(1024)
void k_scan_b(const int* __restrict__ btot, int* __restrict__ bbase,
              int nbkt, int e) {
    __shared__ int s[1024];
    int v = (threadIdx.x < nbkt) ? btot[threadIdx.x] : 0;
    s[threadIdx.x] = v;
    __syncthreads();
    for (int ofs = 1; ofs < 1024; ofs <<= 1) {
        int t = (threadIdx.x >= ofs) ? s[threadIdx.x - ofs] : 0;
        __syncthreads();
        s[threadIdx.x] += t;
        __syncthreads();
    }
    if (threadIdx.x < nbkt) bbase[threadIdx.x] = s[threadIdx.x] - v;
    if (threadIdx.x == 0) bbase[nbkt] = e;
}

__global__ __launch_bounds__(THREADS)
void k_scatter_bkt(const int* __restrict__ src, const int* __restrict__ dst,
                   const int* __restrict__ offs_part, const int* __restrict__ bbase,
                   int* __restrict__ gpack, int e, int nbkt, int chunk) {
    __shared__ int curs[MAXB];
    for (int t = threadIdx.x; t < nbkt; t += THREADS)
        curs[t] = bbase[t] + offs_part[(size_t)blockIdx.x * nbkt + t];
    __syncthreads();
    int beg = blockIdx.x * chunk;
    int end = min(e, beg + chunk);
    for (int base = beg; base < end; base += THREADS * EPT) {
        int i = base + (int)threadIdx.x * EPT;
        if (i + EPT <= end) {
            int4 s0 = *(const int4*)(src + i);
            int4 s1 = *(const int4*)(src + i + 4);
            int4 d0 = *(const int4*)(dst + i);
            int4 d1 = *(const int4*)(dst + i + 4);
            int p0 = atomicAdd(&curs[d0.x >> BSHIFT], 1);
            int p1 = atomicAdd(&curs[d0.y >> BSHIFT], 1);
            int p2 = atomicAdd(&curs[d0.z >> BSHIFT], 1);
            int p3 = atomicAdd(&curs[d0.w >> BSHIFT], 1);
            int p4 = atomicAdd(&curs[d1.x >> BSHIFT], 1);
            int p5 = atomicAdd(&curs[d1.y >> BSHIFT], 1);
            int p6 = atomicAdd(&curs[d1.z >> BSHIFT], 1);
            int p7 = atomicAdd(&curs[d1.w >> BSHIFT], 1);
            gpack[p0] = (s0.x << BSHIFT) | (d0.x & (NPB - 1));
            gpack[p1] = (s0.y << BSHIFT) | (d0.y & (NPB - 1));
            gpack[p2] = (s0.z << BSHIFT) | (d0.z & (NPB - 1));
            gpack[p3] = (s0.w << BSHIFT) | (d0.w & (NPB - 1));
            gpack[p4] = (s1.x << BSHIFT) | (d1.x & (NPB - 1));
            gpack[p5] = (s1.y << BSHIFT) | (d1.y & (NPB - 1));
            gpack[p6] = (s1.z << BSHIFT) | (d1.z & (NPB - 1));
            gpack[p7] = (s1.w << BSHIFT) | (d1.w & (NPB - 1));
        } else {
            for (int k = i; k < end; k++) {
                int d = dst[k];
                int p = atomicAdd(&curs[d >> BSHIFT], 1);
                gpack[p] = (src[k] << BSHIFT) | (d & (NPB - 1));
            }
        }
    }
}

// ---- rowptr2/dinv from per-bucket (node, src-shard) histogram (no fill) ----
__global__ __launch_bounds__(THREADS)
void k_rowptr2(const int* __restrict__ gpack, const int* __restrict__ bbase,
               int* __restrict__ rowptr2, float* __restrict__ dinv,
               int n, int nbkt) {
    __shared__ int hist2[NPB * NSHARD];  // 512
    __shared__ int scn[THREADS];
    int b = blockIdx.x;
    int node0 = b << BSHIFT;
    int nnodes = min(NPB, n - node0);
    int ebeg = bbase[b];
    int eend = bbase[b + 1];
    int tid = threadIdx.x;

    for (int t = tid; t < NPB * NSHARD; t += THREADS) hist2[t] = 0;
    __syncthreads();
    for (int i = ebeg + tid; i < eend; i += THREADS) {
        int g = gpack[i];
        int key = (g & (NPB - 1)) * NSHARD + ((g >> BSHIFT) >> SSHIFT);
        atomicAdd(&hist2[key], 1);
    }
    __syncthreads();
    int v0 = 0, v1 = 0, v2 = 0, v3 = 0, tsum = 0;
    if (tid < NPB) {
        v0 = hist2[tid * NSHARD + 0];
        v1 = hist2[tid * NSHARD + 1];
        v2 = hist2[tid * NSHARD + 2];
        v3 = hist2[tid * NSHARD + 3];
        tsum = v0 + v1 + v2 + v3;
    }
    scn[tid] = tsum;
    __syncthreads();
    for (int ofs = 1; ofs < THREADS; ofs <<= 1) {
        int t = (tid >= ofs) ? scn[tid - ofs] : 0;
        __syncthreads();
        scn[tid] += t;
        __syncthreads();
    }
    int excl = scn[tid] - tsum;
    if (tid < nnodes) {
        int nd = node0 + tid;
        rowptr2[(size_t)nd * NSHARD + 0] = ebeg + excl;
        rowptr2[(size_t)nd * NSHARD + 1] = ebeg + excl + v0;
        rowptr2[(size_t)nd * NSHARD + 2] = ebeg + excl + v0 + v1;
        rowptr2[(size_t)nd * NSHARD + 3] = ebeg + excl + v0 + v1 + v2;
        dinv[nd] = 1.0f / sqrtf((float)(tsum + 1));
    }
    if (b == nbkt - 1 && tid == 0) rowptr2[(size_t)n * NSHARD] = eend;
}

// ---- csr fill: whole-bucket LDS staging -> one sequential store ----
__global__ __launch_bounds__(THREADS)
void k_fill_staged(const int* __restrict__ gpack, const int* __restrict__ bbase,
                   const int* __restrict__ rowptr2, int* __restrict__ csr,
                   int n, int nbkt) {
    __shared__ int curs[NPB * NSHARD];   // 2 KB
    __shared__ int staged[STAGE_CAP];    // 40 KB
    int b = blockIdx.x;
    int node0 = b << BSHIFT;
    int tid = threadIdx.x;
    int ebeg = bbase[b];
    int eend = bbase[b + 1];
    int len = eend - ebeg;

    for (int t = tid; t < NPB * NSHARD; t += THREADS) {
        int nd = node0 + (t >> 2);
        curs[t] = (nd < n) ? rowptr2[(size_t)nd * NSHARD + (t & 3)] : 0;
    }
    __syncthreads();

    if (len <= STAGE_CAP) {
        for (int i = ebeg + tid; i < eend; i += THREADS) {
            int g = gpack[i];
            int key = (g & (NPB - 1)) * NSHARD + ((g >> BSHIFT) >> SSHIFT);
            int pos = atomicAdd(&curs[key], 1);
            staged[pos - ebeg] = g >> BSHIFT;
        }
        __syncthreads();
        for (int i = tid; i < len; i += THREADS)
            csr[ebeg + i] = staged[i];
    } else {
        // pathological bucket: direct (slow but correct)
        for (int i = ebeg + tid; i < eend; i += THREADS) {
            int g = gpack[i];
            int key = (g & (NPB - 1)) * NSHARD + ((g >> BSHIFT) >> SSHIFT);
            int pos = atomicAdd(&curs[key], 1);
            csr[pos] = g >> BSHIFT;
        }
    }
}

// ====================== layer kernels =======================================

__global__ __launch_bounds__(THREADS)
void k_layer_in(const float* __restrict__ x, const float* __restrict__ W,
                const float* __restrict__ dinv, float* __restrict__ hp, int n) {
    __shared__ float sW[34 * 16];
    for (int t = threadIdx.x; t < 34 * 16; t += THREADS) sW[t] = W[t];
    __syncthreads();
    int i = blockIdx.x * THREADS + threadIdx.x;
    if (i >= n) return;
    float di = dinv[i];
    float acc[16];
    #pragma unroll
    for (int j = 0; j < 16; j++) acc[j] = 0.0f;
    const float* xi = x + (size_t)i * 34;
    #pragma unroll
    for (int k = 0; k < 34; k++) {
        float xk = xi[k];
        #pragma unroll
        for (int j = 0; j < 16; j++) acc[j] = fmaf(xk, sW[k * 16 + j], acc[j]);
    }
    float4* o = (float4*)(hp + (size_t)i * 16);
    o[0] = make_float4(acc[0] * di, acc[1] * di, acc[2] * di, acc[3] * di);
    o[1] = make_float4(acc[4] * di, acc[5] * di, acc[6] * di, acc[7] * di);
    o[2] = make_float4(acc[8] * di, acc[9] * di, acc[10] * di, acc[11] * di);
    o[3] = make_float4(acc[12] * di, acc[13] * di, acc[14] * di, acc[15] * di);
}

__global__ __launch_bounds__(THREADS)
void k_layer_mid2(const float* __restrict__ part, const float* __restrict__ W,
                  const float* __restrict__ bprev, const float* __restrict__ dinv,
                  float* __restrict__ hp, int n) {
    __shared__ float sW[16 * 16];
    __shared__ float sB[16];
    for (int t = threadIdx.x; t < 16 * 16; t += THREADS) sW[t] = W[t];
    if (threadIdx.x < 16) sB[threadIdx.x] = bprev[threadIdx.x];
    __syncthreads();
    int i = blockIdx.x * THREADS + threadIdx.x;
    if (i >= n) return;
    float di = dinv[i];
    size_t stride = (size_t)n * 4;   // float4 stride between shard planes
    const float4* p = (const float4*)(part + (size_t)i * 16);
    float4 a0 = p[0], a1 = p[1], a2 = p[2], a3 = p[3];
    #pragma unroll
    for (int s = 1; s < NSHARD; s++) {
        float4 q0 = p[s * stride + 0], q1 = p[s * stride + 1];
        float4 q2 = p[s * stride + 2], q3 = p[s * stride + 3];
        a0.x += q0.x; a0.y += q0.y; a0.z += q0.z; a0.w += q0.w;
        a1.x += q1.x; a1.y += q1.y; a1.z += q1.z; a1.w += q1.w;
        a2.x += q2.x; a2.y += q2.y; a2.z += q2.z; a2.w += q2.w;
        a3.x += q3.x; a3.y += q3.y; a3.z += q3.z; a3.w += q3.w;
    }
    float xin[16] = {a0.x, a0.y, a0.z, a0.w, a1.x, a1.y, a1.z, a1.w,
                     a2.x, a2.y, a2.z, a2.w, a3.x, a3.y, a3.z, a3.w};
    #pragma unroll
    for (int k = 0; k < 16; k++)
        xin[k] = fmaxf(fmaf(di, xin[k], sB[k]), 0.0f);
    float acc[16];
    #pragma unroll
    for (int j = 0; j < 16; j++) acc[j] = 0.0f;
    #pragma unroll
    for (int k = 0; k < 16; k++) {
        float xk = xin[k];
        #pragma unroll
        for (int j = 0; j < 16; j++) acc[j] = fmaf(xk, sW[k * 16 + j], acc[j]);
    }
    float4* o = (float4*)(hp + (size_t)i * 16);
    o[0] = make_float4(acc[0] * di, acc[1] * di, acc[2] * di, acc[3] * di);
    o[1] = make_float4(acc[4] * di, acc[5] * di, acc[6] * di, acc[7] * di);
    o[2] = make_float4(acc[8] * di, acc[9] * di, acc[10] * di, acc[11] * di);
    o[3] = make_float4(acc[12] * di, acc[13] * di, acc[14] * di, acc[15] * di);
}

__global__ __launch_bounds__(THREADS)
void k_layer_last2(const float* __restrict__ part, const float* __restrict__ W,
                   const float* __restrict__ bprev, const float* __restrict__ dinv,
                   float* __restrict__ hp4, int n) {
    __shared__ float sW[16 * 4];
    __shared__ float sB[16];
    for (int t = threadIdx.x; t < 16 * 4; t += THREADS) sW[t] = W[t];
    if (threadIdx.x < 16) sB[threadIdx.x] = bprev[threadIdx.x];
    __syncthreads();
    int i = blockIdx.x * THREADS + threadIdx.x;
    if (i >= n) return;
    float di = dinv[i];
    size_t stride = (size_t)n * 4;
    const float4* p = (const float4*)(part + (size_t)i * 16);
    float4 a0 = p[0], a1 = p[1], a2 = p[2], a3 = p[3];
    #pragma unroll
    for (int s = 1; s < NSHARD; s++) {
        float4 q0 = p[s * stride + 0], q1 = p[s * stride + 1];
        float4 q2 = p[s * stride + 2], q3 = p[s * stride + 3];
        a0.x += q0.x; a0.y += q0.y; a0.z += q0.z; a0.w += q0.w;
        a1.x += q1.x; a1.y += q1.y; a1.z += q1.z; a1.w += q1.w;
        a2.x += q2.x; a2.y += q2.y; a2.z += q2.z; a2.w += q2.w;
        a3.x += q3.x; a3.y += q3.y; a3.z += q3.z; a3.w += q3.w;
    }
    float xin[16] = {a0.x, a0.y, a0.z, a0.w, a1.x, a1.y, a1.z, a1.w,
                     a2.x, a2.y, a2.z, a2.w, a3.x, a3.y, a3.z, a3.w};
    #pragma unroll
    for (int k = 0; k < 16; k++)
        xin[k] = fmaxf(fmaf(di, xin[k], sB[k]), 0.0f);
    float acc[4];
    #pragma unroll
    for (int j = 0; j < 4; j++) acc[j] = 0.0f;
    #pragma unroll
    for (int k = 0; k < 16; k++) {
        float xk = xin[k];
        #pragma unroll
        for (int j = 0; j < 4; j++) acc[j] = fmaf(xk, sW[k * 4 + j], acc[j]);
    }
    *(float4*)(hp4 + (size_t)i * 4) =
        make_float4(acc[0] * di, acc[1] * di, acc[2] * di, acc[3] * di);
}

// ====================== sharded gather (pipelined, r9-proven) ===============

__global__ __launch_bounds__(THREADS, 8)
void k_gather16s(const int* __restrict__ rowptr2, const int* __restrict__ csr,
                 const float* __restrict__ hp, float* __restrict__ part, int n) {
    int shard = blockIdx.x & (NSHARD - 1);
    int rg    = blockIdx.x >> 2;
    int row   = rg * 16 + ((int)threadIdx.x >> 4);
    int lane  = threadIdx.x & 15;
    if (row >= n) return;
    int base = (threadIdx.x & 63) & ~15;

    int beg = rowptr2[(size_t)row * NSHARD + shard];
    int end = rowptr2[(size_t)row * NSHARD + shard + 1];
    int len = end - beg;

    float a0 = ((row >> SSHIFT) == shard) ? hp[(size_t)row * 16 + lane] : 0.0f;
    float a1 = 0.f, a2 = 0.f, a3 = 0.f;

    int s0 = 0, s1 = 0;
    if (len > 0)  s0 = csr[min(beg + lane, end - 1)];
    if (len > 16) s1 = csr[min(beg + 16 + lane, end - 1)];

    {   // chunk 0 (cnt = len, predicated)
        int cnt = len;
        #pragma unroll
        for (int k = 0; k < 16; k += 4) {
            int sk0 = __shfl(s0, base + k + 0, 64);
            int sk1 = __shfl(s0, base + k + 1, 64);
            int sk2 = __shfl(s0, base + k + 2, 64);
            int sk3 = __shfl(s0, base + k + 3, 64);
            float v0 = hp[(size_t)sk0 * 16 + lane];
            float v1 = hp[(size_t)sk1 * 16 + lane];
            float v2 = hp[(size_t)sk2 * 16 + lane];
            float v3 = hp[(size_t)sk3 * 16 + lane];
            a0 += (k + 0 < cnt) ? v0 : 0.0f;
            a1 += (k + 1 < cnt) ? v1 : 0.0f;
            a2 += (k + 2 < cnt) ? v2 : 0.0f;
            a3 += (k + 3 < cnt) ? v3 : 0.0f;
        }
    }
    {   // chunk 1 (cnt = len-16)
        int cnt = len - 16;
        #pragma unroll
        for (int k = 0; k < 16; k += 4) {
            int sk0 = __shfl(s1, base + k + 0, 64);
            int sk1 = __shfl(s1, base + k + 1, 64);
            int sk2 = __shfl(s1, base + k + 2, 64);
            int sk3 = __shfl(s1, base + k + 3, 64);
            float v0 = hp[(size_t)sk0 * 16 + lane];
            float v1 = hp[(size_t)sk1 * 16 + lane];
            float v2 = hp[(size_t)sk2 * 16 + lane];
            float v3 = hp[(size_t)sk3 * 16 + lane];
            a0 += (k + 0 < cnt) ? v0 : 0.0f;
            a1 += (k + 1 < cnt) ? v1 : 0.0f;
            a2 += (k + 2 < cnt) ? v2 : 0.0f;
            a3 += (k + 3 < cnt) ? v3 : 0.0f;
        }
    }
    for (int e = beg + 32; e < end; e += 16) {   // rare tail (len > 32)
        int s = csr[min(e + lane, end - 1)];
        int cnt = end - e;
        #pragma unroll
        for (int k = 0; k < 16; k += 4) {
            int sk0 = __shfl(s, base + k + 0, 64);
            int sk1 = __shfl(s, base + k + 1, 64);
            int sk2 = __shfl(s, base + k + 2, 64);
            int sk3 = __shfl(s, base + k + 3, 64);
            float v0 = hp[(size_t)sk0 * 16 + lane];
            float v1 = hp[(size_t)sk1 * 16 + lane];
            float v2 = hp[(size_t)sk2 * 16 + lane];
            float v3 = hp[(size_t)sk3 * 16 + lane];
            a0 += (k + 0 < cnt) ? v0 : 0.0f;
            a1 += (k + 1 < cnt) ? v1 : 0.0f;
            a2 += (k + 2 < cnt) ? v2 : 0.0f;
            a3 += (k + 3 < cnt) ? v3 : 0.0f;
        }
    }
    part[((size_t)shard * n + row) * 16 + lane] = (a0 + a1) + (a2 + a3);
}

__global__ __launch_bounds__(THREADS, 8)
void k_gather4_final(const int* __restrict__ rowptr2, const int* __restrict__ csr,
                     const float* __restrict__ hp, float* __restrict__ outp,
                     const float* __restrict__ dinv, const float* __restrict__ bias,
                     int n) {
    int tid = blockIdx.x * THREADS + threadIdx.x;
    int row = tid >> 4;
    int sub = threadIdx.x & 15;
    int e4  = sub >> 2;   // edge slot 0..3
    int ch  = sub & 3;    // channel 0..3
    if (row >= n) return;
    int base = (threadIdx.x & 63) & ~15;

    int beg = rowptr2[(size_t)row * NSHARD];
    int end = rowptr2[(size_t)(row + 1) * NSHARD];
    int len = end - beg;

    float a = (e4 == 0) ? hp[(size_t)row * 4 + ch] : 0.0f;  // self-loop once

    int s0 = 0, s1 = 0;
    if (len > 0)  s0 = csr[min(beg + sub, end - 1)];
    if (len > 16) s1 = csr[min(beg + 16 + sub, end - 1)];

    {   // chunk 0
        int cnt = len;
        #pragma unroll
        for (int k = 0; k < 4; k++) {
            int idx = k * 4 + e4;
            int sk = __shfl(s0, base + idx, 64);
            float v = hp[(size_t)sk * 4 + ch];
            a += (idx < cnt) ? v : 0.0f;
        }
    }
    {   // chunk 1
        int cnt = len - 16;
        #pragma unroll
        for (int k = 0; k < 4; k++) {
            int idx = k * 4 + e4;
            int sk = __shfl(s1, base + idx, 64);
            float v = hp[(size_t)sk * 4 + ch];
            a += (idx < cnt) ? v : 0.0f;
        }
    }
    for (int e = beg + 32; e < end; e += 16) {
        int s = csr[min(e + sub, end - 1)];
        int cnt = end - e;
        #pragma unroll
        for (int k = 0; k < 4; k++) {
            int idx = k * 4 + e4;
            int sk = __shfl(s, base + idx, 64);
            float v = hp[(size_t)sk * 4 + ch];
            a += (idx < cnt) ? v : 0.0f;
        }
    }
    a += __shfl_xor(a, 4, 64);
    a += __shfl_xor(a, 8, 64);
    if (e4 == 0) outp[(size_t)row * 4 + ch] = fmaf(dinv[row], a, bias[ch]);
}

// ========================= fallback path kernels ============================

__global__ __launch_bounds__(THREADS)
void k_zero(int* __restrict__ p, int n) {
    int i = blockIdx.x * THREADS + threadIdx.x;
    if (i < n) p[i] = 0;
}

__global__ __launch_bounds__(THREADS)
void k_count_deg(const int* __restrict__ dst, int* __restrict__ deg, int e) {
    int i = blockIdx.x * THREADS + threadIdx.x;
    if (i >= e) return;
    atomicAdd(&deg[dst[i]], 1);
}

__global__ __launch_bounds__(THREADS)
void k_dinv(const int* __restrict__ deg, float* __restrict__ dinv, int n) {
    int i = blockIdx.x * THREADS + threadIdx.x;
    if (i < n) dinv[i] = 1.0f / sqrtf((float)(deg[i] + 1));
}

__global__ __launch_bounds__(THREADS)
void k_scan1(const int* __restrict__ deg, int* __restrict__ rowptr,
             int* __restrict__ bsum, int n) {
    __shared__ int s[THREADS];
    int i = blockIdx.x * THREADS + threadIdx.x;
    int v = (i < n) ? deg[i] : 0;
    s[threadIdx.x] = v;
    __syncthreads();
    for (int ofs = 1; ofs < THREADS; ofs <<= 1) {
        int t = (threadIdx.x >= ofs) ? s[threadIdx.x - ofs] : 0;
        __syncthreads();
        s[threadIdx.x] += t;
        __syncthreads();
    }
    if (i < n) rowptr[i] = s[threadIdx.x] - v;
    if (threadIdx.x == THREADS - 1) bsum[blockIdx.x] = s[THREADS - 1];
}

__global__ __launch_bounds__(1024)
void k_scan2(int* __restrict__ bsum, int nb) {
    __shared__ int s[1024];
    int v = (threadIdx.x < nb) ? bsum[threadIdx.x] : 0;
    s[threadIdx.x] = v;
    __syncthreads();
    for (int ofs = 1; ofs < 1024; ofs <<= 1) {
        int t = (threadIdx.x >= ofs) ? s[threadIdx.x - ofs] : 0;
        __syncthreads();
        s[threadIdx.x] += t;
        __syncthreads();
    }
    if (threadIdx.x < nb) bsum[threadIdx.x] = s[threadIdx.x] - v;
}

__global__ __launch_bounds__(THREADS)
void k_scan3(int* __restrict__ rowptr, const int* __restrict__ bsum,
             int* __restrict__ cursor, int n, int e) {
    int i = blockIdx.x * THREADS + threadIdx.x;
    if (i < n) {
        int r = rowptr[i] + bsum[blockIdx.x];
        rowptr[i] = r;
        cursor[i] = r;
    }
    if (i == 0) rowptr[n] = e;
}

__global__ __launch_bounds__(THREADS)
void k_fill_cursor(const int* __restrict__ src, const int* __restrict__ dst,
                   int* __restrict__ cursor, int* __restrict__ csr, int e) {
    int i = blockIdx.x * THREADS + threadIdx.x;
    if (i >= e) return;
    int pos = atomicAdd(&cursor[dst[i]], 1);
    csr[pos] = src[i];
}

template<int DIN, int DOUT, bool TRANSFORM>
__global__ __launch_bounds__(THREADS)
void k_layer(const float* __restrict__ in, const float* __restrict__ W,
             const float* __restrict__ bprev, const float* __restrict__ dinv,
             float* __restrict__ hp, int n) {
    __shared__ float sW[DIN * DOUT];
    for (int t = threadIdx.x; t < DIN * DOUT; t += THREADS) sW[t] = W[t];
    __syncthreads();
    int i = blockIdx.x * THREADS + threadIdx.x;
    if (i >= n) return;
    float di = dinv[i];
    float xin[DIN];
    #pragma unroll
    for (int k = 0; k < DIN; k++) xin[k] = in[(size_t)i * DIN + k];
    if constexpr (TRANSFORM) {
        #pragma unroll
        for (int k = 0; k < DIN; k++)
            xin[k] = fmaxf(fmaf(di, xin[k], bprev[k]), 0.0f);
    }
    float acc[DOUT];
    #pragma unroll
    for (int j = 0; j < DOUT; j++) acc[j] = 0.0f;
    #pragma unroll
    for (int k = 0; k < DIN; k++) {
        float xk = xin[k];
        #pragma unroll
        for (int j = 0; j < DOUT; j++) acc[j] = fmaf(xk, sW[k * DOUT + j], acc[j]);
    }
    #pragma unroll
    for (int j = 0; j < DOUT; j++) hp[(size_t)i * DOUT + j] = acc[j] * di;
}

template<int D, bool FINAL>
__global__ __launch_bounds__(THREADS)
void k_gather(const int* __restrict__ rowptr, const int* __restrict__ csr,
              const float* __restrict__ hp, float* __restrict__ outp,
              const float* __restrict__ dinv, const float* __restrict__ bias,
              int n) {
    int tid  = blockIdx.x * THREADS + threadIdx.x;
    int row  = tid / D;
    int lane = tid & (D - 1);
    if (row >= n) return;
    int base = (threadIdx.x & 63) & ~(D - 1);
    int beg = rowptr[row];
    int end = rowptr[row + 1];
    float a0 = hp[(size_t)row * D + lane];
    float a1 = 0.f, a2 = 0.f, a3 = 0.f;
    int e = beg;
    for (; e + D <= end; e += D) {
        int s = csr[e + lane];
        #pragma unroll
        for (int k = 0; k < D; k += 4) {
            int s0 = __shfl(s, base + k + 0, 64);
            int s1 = __shfl(s, base + k + 1, 64);
            int s2 = __shfl(s, base + k + 2, 64);
            int s3 = __shfl(s, base + k + 3, 64);
            a0 += hp[(size_t)s0 * D + lane];
            a1 += hp[(size_t)s1 * D + lane];
            a2 += hp[(size_t)s2 * D + lane];
            a3 += hp[(size_t)s3 * D + lane];
        }
    }
    if (e < end) {
        int idx = e + lane;
        int s = (idx < end) ? csr[idx] : 0;
        int cnt = end - e;
        for (int k = 0; k < cnt; k++) {
            int sk = __shfl(s, base + k, 64);
            a0 += hp[(size_t)sk * D + lane];
        }
    }
    float acc = (a0 + a1) + (a2 + a3);
    if constexpr (FINAL) {
        outp[(size_t)row * D + lane] = fmaf(dinv[row], acc, bias[lane]);
    } else {
        outp[(size_t)row * D + lane] = acc;
    }
}

// ---------------------------------------------------------------------------

extern "C" void kernel_launch(void* const* d_in, const int* in_sizes, int n_in,
                              void* d_out, int out_size, void* d_ws, size_t ws_size,
                              hipStream_t stream) {
    const float* x   = (const float*)d_in[0];
    const int*   ei  = (const int*)d_in[1];   // int32 per harness conversion
    const float* W1  = (const float*)d_in[2];
    const float* b1  = (const float*)d_in[3];
    const float* W2  = (const float*)d_in[4];
    const float* b2  = (const float*)d_in[5];
    const float* W3  = (const float*)d_in[6];
    const float* b3  = (const float*)d_in[7];
    const float* W4  = (const float*)d_in[8];
    const float* b4  = (const float*)d_in[9];
    float*       out = (float*)d_out;

    const int N = in_sizes[0] / 34;
    const int E = in_sizes[1] / 2;
    const int* src = ei;
    const int* dst = ei + E;

    const int gN  = (N + THREADS - 1) / THREADS;

    const int nbkt  = (N + NPB - 1) >> BSHIFT;
    const int chunk = (((E + NCHUNK - 1) / NCHUNK) + EPT - 1) & ~(EPT - 1);
    const int gG    = ((N + 15) / 16) * NSHARD;                        // sharded gather
    const int gF    = (int)(((size_t)N * 16 + THREADS - 1) / THREADS); // final gather

    // ---- fast-path carve ----
    {
        char* ws = (char*)d_ws;
        size_t off = 0;
        auto alloc = [&](size_t bytes) -> void* {
            void* p = ws + off;
            off += (bytes + 255) & ~(size_t)255;
            return p;
        };
        float* dinv    = (float*)alloc((size_t)N * 4);
        float* hp      = (float*)alloc((size_t)N * 16 * 4);
        float* part    = (float*)alloc((size_t)NSHARD * N * 16 * 4);
        float* hp4     = (float*)alloc((size_t)N * 4 * 4);
        int*   rowptr2 = (int*)  alloc(((size_t)N * NSHARD + 1) * 4);
        int*   csr     = (int*)  alloc((size_t)E * 4);
        int*   gpack   = (int*)  alloc((size_t)E * 4);
        int*   offsp   = (int*)  alloc((size_t)NCHUNK * nbkt * 4);
        int*   btot    = (int*)  alloc((size_t)nbkt * 4);
        int*   bbase   = (int*)  alloc((size_t)(nbkt + 1) * 4);

        bool aligned16 = (((uintptr_t)src & 15) == 0) && (((uintptr_t)dst & 15) == 0);
        bool fast_ok = (nbkt <= MAXB) && (off <= ws_size) && aligned16 &&
                       (N <= (1 << (31 - BSHIFT - 1))) &&   // src<<7 no overflow
                       (N <= (NSHARD << SSHIFT));           // shard id < NSHARD

        if (fast_ok) {
            // ---- counting-sort CSR build ----
            k_hist        <<<NCHUNK, THREADS, 0, stream>>>(dst, offsp, E, nbkt, chunk);
            k_colscan     <<<nbkt, NCHUNK, 0, stream>>>(offsp, btot, nbkt);
            k_scan_b      <<<1, 1024, 0, stream>>>(btot, bbase, nbkt, E);
            k_scatter_bkt <<<NCHUNK, THREADS, 0, stream>>>(src, dst, offsp, bbase,
                                                           gpack, E, nbkt, chunk);
            k_rowptr2     <<<nbkt, THREADS, 0, stream>>>(gpack, bbase, rowptr2,
                                                         dinv, N, nbkt);
            k_fill_staged <<<nbkt, THREADS, 0, stream>>>(gpack, bbase, rowptr2,
                                                         csr, N, nbkt);

            // ---- layers ----
            k_layer_in <<<gN, THREADS, 0, stream>>>(x, W1, dinv, hp, N);
            k_gather16s<<<gG, THREADS, 0, stream>>>(rowptr2, csr, hp, part, N);

            k_layer_mid2<<<gN, THREADS, 0, stream>>>(part, W2, b1, dinv, hp, N);
            k_gather16s<<<gG, THREADS, 0, stream>>>(rowptr2, csr, hp, part, N);

            k_layer_mid2<<<gN, THREADS, 0, stream>>>(part, W3, b2, dinv, hp, N);
            k_gather16s<<<gG, THREADS, 0, stream>>>(rowptr2, csr, hp, part, N);

            k_layer_last2<<<gN, THREADS, 0, stream>>>(part, W4, b3, dinv, hp4, N);
            k_gather4_final<<<gF, THREADS, 0, stream>>>(rowptr2, csr, hp4, out,
                                                        dinv, b4, N);
            return;
        }
    }

    // ---- fallback: cursor-atomic CSR path, unified layout ----
    {
        char* ws = (char*)d_ws;
        size_t off = 0;
        auto alloc = [&](size_t bytes) -> void* {
            void* p = ws + off;
            off += (bytes + 255) & ~(size_t)255;
            return p;
        };
        int*   deg    = (int*)  alloc((size_t)N * 4);
        float* dinv   = (float*)alloc((size_t)N * 4);
        float* bufA   = (float*)alloc((size_t)N * 16 * 4);
        float* bufB   = (float*)alloc((size_t)N * 16 * 4);
        int*   rowptr = (int*)  alloc((size_t)(N + 1) * 4);
        int*   cursor = (int*)  alloc((size_t)N * 4);
        const int nb  = (N + THREADS - 1) / THREADS;
        int*   bsum   = (int*)  alloc((size_t)nb * 4);
        int*   csr    = (int*)  alloc((size_t)E * 4);

        const int gE  = (E + THREADS - 1) / THREADS;
        const int g16 = (int)(((size_t)N * 16 + THREADS - 1) / THREADS);
        const int g4  = (int)(((size_t)N * 4 + THREADS - 1) / THREADS);

        k_zero<<<gN, THREADS, 0, stream>>>(deg, N);
        k_count_deg<<<gE, THREADS, 0, stream>>>(dst, deg, E);
        k_dinv<<<gN, THREADS, 0, stream>>>(deg, dinv, N);
        k_scan1<<<nb, THREADS, 0, stream>>>(deg, rowptr, bsum, N);
        k_scan2<<<1, 1024, 0, stream>>>(bsum, nb);
        k_scan3<<<nb, THREADS, 0, stream>>>(rowptr, bsum, cursor, N, E);
        k_fill_cursor<<<gE, THREADS, 0, stream>>>(src, dst, cursor, csr, E);

        k_layer<34, 16, false><<<gN, THREADS, 0, stream>>>(x, W1, nullptr, dinv, bufA, N);
        k_gather<16, false><<<g16, THREADS, 0, stream>>>(rowptr, csr, bufA, bufB, nullptr, nullptr, N);

        k_layer<16, 16, true><<<gN, THREADS, 0, stream>>>(bufB, W2, b1, dinv, bufA, N);
        k_gather<16, false><<<g16, THREADS, 0, stream>>>(rowptr, csr, bufA, bufB, nullptr, nullptr, N);

        k_layer<16, 16, true><<<gN, THREADS, 0, stream>>>(bufB, W3, b2, dinv, bufA, N);
        k_gather<16, false><<<g16, THREADS, 0, stream>>>(rowptr, csr, bufA, bufB, nullptr, nullptr, N);

        k_layer<16, 4, true><<<gN, THREADS, 0, stream>>>(bufB, W4, b3, dinv, bufA, N);
        k_gather<4, true><<<g4, THREADS, 0, stream>>>(rowptr, csr, bufA, out, dinv, b4, N);
    }
}